// Round 1
// baseline (468.646 us; speedup 1.0000x reference)
//
#include <hip/hip_runtime.h>

// IntersectionGNN: out = L2(L1(x)) with L(x) = relu([max_nbr(x) | x] @ W^T + b)
// B=4, N=50000, D=8, F=128, K=2F=256.
//
// Design (round 1):
//  - GEMM via f16 hi/lo split MFMA (hi*hi + hi*lo + lo*hi), error ~2^-21 rel.
//  - setup kernel pre-splits W1/W2 into f16 hi/lo, layout [o][k] (MFMA B-frag native).
//  - layer kernel: TILE_M=64 nodes/block, 256 thr (4 waves), wave owns 32 output cols.
//    gather-max coalesced (half-wave per node, float4 rows); cc staged hi/lo in 64KB LDS
//    with XOR swizzle ((row&7)<<4) to break stride-512B bank conflicts on ds_read_b128.
//    W frags live in registers (reloaded once at K-midpoint to cap VGPR ~190).
//  - d_ws: [inter (102.4 MB) | W1h W1l W2h W2l (256 KB)].

#define N_NODES 50000
#define N_BATCH 4
#define DEG 8
#define FDIM 128
#define K2 256
#define TILE_M 64

typedef _Float16 f16x8 __attribute__((ext_vector_type(8)));
typedef _Float16 f16x4 __attribute__((ext_vector_type(4)));
typedef float f32x4 __attribute__((ext_vector_type(4)));

__global__ void split_w_kernel(const float* __restrict__ W1, const float* __restrict__ W2,
                               _Float16* __restrict__ w1h, _Float16* __restrict__ w1l,
                               _Float16* __restrict__ w2h, _Float16* __restrict__ w2l) {
  const int i = blockIdx.x * 256 + threadIdx.x;  // grid exactly covers 128*256 = 32768
  {
    const float a = W1[i];
    const _Float16 h = (_Float16)a;
    w1h[i] = h;
    w1l[i] = (_Float16)(a - (float)h);
  }
  {
    const float a = W2[i];
    const _Float16 h = (_Float16)a;
    w2h[i] = h;
    w2l[i] = (_Float16)(a - (float)h);
  }
}

__global__ __launch_bounds__(256, 2)
void gnn_layer_kernel(const float* __restrict__ xin, const int* __restrict__ adj,
                      const _Float16* __restrict__ Wh, const _Float16* __restrict__ Wl,
                      const float* __restrict__ bias, float* __restrict__ out) {
  __shared__ unsigned char lds[65536];  // cc_hi [64][512B swizzled] @0, cc_lo @32768

  const int tid = (int)threadIdx.x;
  const int b   = (int)blockIdx.y;
  const int n0  = (int)blockIdx.x * TILE_M;

  const int l   = tid & 63;
  const int wv  = tid >> 6;   // wave 0..3 -> output cols [wv*32, wv*32+32)
  const int col = l & 15;
  const int kg  = l >> 4;
  const int o0  = wv * 32;

  // ---- B fragments (W), first K-half k=[0,128), in registers ----
  f16x8 Bh[2][4], Bl[2][4];
  #pragma unroll
  for (int of = 0; of < 2; ++of) {
    #pragma unroll
    for (int kt = 0; kt < 4; ++kt) {
      const int o = o0 + of * 16 + col;
      const int k = kt * 32 + kg * 8;
      Bh[of][kt] = *(const f16x8*)(Wh + o * K2 + k);
      Bl[of][kt] = *(const f16x8*)(Wl + o * K2 + k);
    }
  }

  // ---- gather-max + concat + f16 hi/lo split into LDS ----
  const int lane32 = tid & 31;
  const int nh     = tid >> 5;  // 8 half-waves, one node each per iter
  const float* xb  = xin + (size_t)b * N_NODES * FDIM;

  for (int it = 0; it < 8; ++it) {
    const int nl = it * 8 + nh;
    const int ng = n0 + nl;
    f32x4 agg = (f32x4){0.f, 0.f, 0.f, 0.f};
    f32x4 xv  = (f32x4){0.f, 0.f, 0.f, 0.f};
    if (ng < N_NODES) {
      agg = (f32x4){-3.0e38f, -3.0e38f, -3.0e38f, -3.0e38f};
      const int* arow = adj + ng * DEG;
      #pragma unroll
      for (int d = 0; d < DEG; ++d) {
        const int nbr = arow[d];
        const f32x4 v = *(const f32x4*)(xb + (size_t)nbr * FDIM + lane32 * 4);
        agg[0] = fmaxf(agg[0], v[0]);
        agg[1] = fmaxf(agg[1], v[1]);
        agg[2] = fmaxf(agg[2], v[2]);
        agg[3] = fmaxf(agg[3], v[3]);
      }
      xv = *(const f32x4*)(xb + (size_t)ng * FDIM + lane32 * 4);
    }
    #pragma unroll
    for (int part = 0; part < 2; ++part) {
      const f32x4 v = part ? xv : agg;  // agg -> k[0,128), x -> k[128,256)
      f16x4 hi, lo;
      #pragma unroll
      for (int j = 0; j < 4; ++j) {
        const _Float16 h = (_Float16)v[j];
        hi[j] = h;
        lo[j] = (_Float16)(v[j] - (float)h);
      }
      const int k    = part * 128 + lane32 * 4;
      const int byte = nl * 512 + ((k * 2) ^ ((nl & 7) << 4));
      *(f16x4*)(lds + byte)         = hi;
      *(f16x4*)(lds + 32768 + byte) = lo;
    }
  }

  __syncthreads();

  // ---- MFMA: D[64x128] = cc[64x256] . W^T via 16x16x32 f16, 3-pass split ----
  f32x4 acc[4][2] = {};
  for (int h2 = 0; h2 < 2; ++h2) {
    if (h2 == 1) {  // reload B frags for K-half k=[128,256)
      #pragma unroll
      for (int of = 0; of < 2; ++of) {
        #pragma unroll
        for (int kt = 0; kt < 4; ++kt) {
          const int o = o0 + of * 16 + col;
          const int k = 128 + kt * 32 + kg * 8;
          Bh[of][kt] = *(const f16x8*)(Wh + o * K2 + k);
          Bl[of][kt] = *(const f16x8*)(Wl + o * K2 + k);
        }
      }
    }
    #pragma unroll
    for (int kt = 0; kt < 4; ++kt) {
      f16x8 Ah[4], Al[4];
      #pragma unroll
      for (int mf = 0; mf < 4; ++mf) {
        const int row  = mf * 16 + col;
        const int k    = h2 * 128 + kt * 32 + kg * 8;
        const int byte = row * 512 + ((k * 2) ^ ((row & 7) << 4));
        Ah[mf] = *(const f16x8*)(lds + byte);
        Al[mf] = *(const f16x8*)(lds + 32768 + byte);
      }
      #pragma unroll
      for (int mf = 0; mf < 4; ++mf) {
        #pragma unroll
        for (int of = 0; of < 2; ++of) {
          acc[mf][of] = __builtin_amdgcn_mfma_f32_16x16x32_f16(Ah[mf], Bh[of][kt], acc[mf][of], 0, 0, 0);
          acc[mf][of] = __builtin_amdgcn_mfma_f32_16x16x32_f16(Ah[mf], Bl[of][kt], acc[mf][of], 0, 0, 0);
          acc[mf][of] = __builtin_amdgcn_mfma_f32_16x16x32_f16(Al[mf], Bh[of][kt], acc[mf][of], 0, 0, 0);
        }
      }
    }
  }

  // ---- epilogue: bias + relu + store (C/D layout: col=lane&15, row=(lane>>4)*4+j) ----
  const float bv0 = bias[o0 + col];
  const float bv1 = bias[o0 + 16 + col];
  #pragma unroll
  for (int mf = 0; mf < 4; ++mf) {
    #pragma unroll
    for (int j = 0; j < 4; ++j) {
      const int nl = mf * 16 + kg * 4 + j;
      const int ng = n0 + nl;
      if (ng < N_NODES) {
        float* orow = out + ((size_t)b * N_NODES + ng) * FDIM;
        const float r0 = acc[mf][0][j] + bv0;
        const float r1 = acc[mf][1][j] + bv1;
        orow[o0 + col]      = r0 > 0.f ? r0 : 0.f;
        orow[o0 + 16 + col] = r1 > 0.f ? r1 : 0.f;
      }
    }
  }
}

extern "C" void kernel_launch(void* const* d_in, const int* in_sizes, int n_in,
                              void* d_out, int out_size, void* d_ws, size_t ws_size,
                              hipStream_t stream) {
  const float* x  = (const float*)d_in[0];
  const int* adj  = (const int*)d_in[1];
  const float* W1 = (const float*)d_in[2];
  const float* b1 = (const float*)d_in[3];
  const float* W2 = (const float*)d_in[4];
  const float* b2 = (const float*)d_in[5];
  float* out      = (float*)d_out;

  char* ws = (char*)d_ws;
  float* inter = (float*)ws;                               // 4*50000*128*4 = 102,400,000 B
  const size_t interB = (size_t)N_BATCH * N_NODES * FDIM * sizeof(float);
  _Float16* w1h = (_Float16*)(ws + interB);
  _Float16* w1l = w1h + 32768;
  _Float16* w2h = w1l + 32768;
  _Float16* w2l = w2h + 32768;

  split_w_kernel<<<128, 256, 0, stream>>>(W1, W2, w1h, w1l, w2h, w2l);

  dim3 grid((N_NODES + TILE_M - 1) / TILE_M, N_BATCH);  // (782, 4)
  gnn_layer_kernel<<<grid, 256, 0, stream>>>(x, adj, w1h, w1l, b1, inter);
  gnn_layer_kernel<<<grid, 256, 0, stream>>>(inter, adj, w2h, w2l, b2, out);
}

// Round 2
// 414.512 us; speedup vs baseline: 1.1306x; 1.1306x over previous
//
#include <hip/hip_runtime.h>

// IntersectionGNN: out = L2(L1(x)) with L(x) = relu([max_nbr(x) | x] @ W^T + b)
// B=4, N=50000, D=8, F=128, K=2F=256.
//
// Round 2 design:
//  - x pre-converted to f16 (halves all gather bytes); inter stored f16.
//  - GEMM: A = f16 cc (lo dropped), W kept as f16 hi/lo -> acc = Ah*Bh + Ah*Bl.
//    Added error ~5e-4, far under the 0.0156 reference-side residual.
//  - LDS halved to 32KB (hi-only cc), B-frags reloaded per kt from L2-resident W
//    -> __launch_bounds__(256,4): 4-5 blocks/CU (vs 2), 2x+ occupancy to hide
//    random-gather latency (round-1 counters: occ 21%, hbm 34%, nothing saturated).
//  - XOR swizzle ((row&7)<<4) on 512B LDS rows kills stride bank conflicts.
//  - d_ws: [xf16 51.2MB][inter16 51.2MB][W splits 256KB].

#define N_NODES 50000
#define N_BATCH 4
#define DEG 8
#define FDIM 128
#define K2 256
#define TILE_M 64

typedef _Float16 f16x8 __attribute__((ext_vector_type(8)));
typedef _Float16 f16x4 __attribute__((ext_vector_type(4)));
typedef float f32x4 __attribute__((ext_vector_type(4)));

__global__ void split_w_kernel(const float* __restrict__ W1, const float* __restrict__ W2,
                               _Float16* __restrict__ w1h, _Float16* __restrict__ w1l,
                               _Float16* __restrict__ w2h, _Float16* __restrict__ w2l) {
  const int i = blockIdx.x * 256 + threadIdx.x;  // grid exactly covers 128*256 = 32768
  {
    const float a = W1[i];
    const _Float16 h = (_Float16)a;
    w1h[i] = h;
    w1l[i] = (_Float16)(a - (float)h);
  }
  {
    const float a = W2[i];
    const _Float16 h = (_Float16)a;
    w2h[i] = h;
    w2l[i] = (_Float16)(a - (float)h);
  }
}

__global__ void cvt_x_kernel(const float* __restrict__ x, _Float16* __restrict__ x16) {
  const size_t i = ((size_t)blockIdx.x * 256 + threadIdx.x) * 4;  // 25000 blocks exact
  const f32x4 v = *(const f32x4*)(x + i);
  f16x4 h;
  #pragma unroll
  for (int j = 0; j < 4; ++j) h[j] = (_Float16)v[j];
  *(f16x4*)(x16 + i) = h;
}

static __device__ inline f16x4 vmax4(f16x4 a, f16x4 b) {
  f16x4 r;
  #pragma unroll
  for (int j = 0; j < 4; ++j) r[j] = a[j] > b[j] ? a[j] : b[j];
  return r;
}

template <bool OUT_F32>
__global__ __launch_bounds__(256, 4)
void gnn_layer_kernel(const _Float16* __restrict__ xin, const int* __restrict__ adj,
                      const _Float16* __restrict__ Wh, const _Float16* __restrict__ Wl,
                      const float* __restrict__ bias, void* __restrict__ out_) {
  __shared__ unsigned char lds[32768];  // cc f16 [64 rows][512B], XOR-swizzled

  const int tid = (int)threadIdx.x;
  const int b   = (int)blockIdx.y;
  const int n0  = (int)blockIdx.x * TILE_M;

  const int l   = tid & 63;
  const int wv  = tid >> 6;   // wave 0..3 -> output cols [wv*32, wv*32+32)
  const int col = l & 15;
  const int kg  = l >> 4;
  const int o0  = wv * 32;

  // ---- gather-max + concat (all f16) into LDS ----
  const int lane32 = tid & 31;
  const int nh     = tid >> 5;  // 8 half-waves, one node each per iter
  const _Float16* xb = xin + (size_t)b * N_NODES * FDIM;

  for (int it = 0; it < 8; ++it) {
    const int nl = it * 8 + nh;
    const int ng = n0 + nl;
    f16x4 agg = (f16x4){0, 0, 0, 0};
    f16x4 xv  = (f16x4){0, 0, 0, 0};
    if (ng < N_NODES) {
      const _Float16 ninf = (_Float16)(-65504.0f);
      agg = (f16x4){ninf, ninf, ninf, ninf};
      const int* arow = adj + ng * DEG;
      #pragma unroll
      for (int d = 0; d < DEG; ++d) {
        const int nbr = arow[d];
        const f16x4 v = *(const f16x4*)(xb + (size_t)nbr * FDIM + lane32 * 4);
        agg = vmax4(agg, v);
      }
      xv = *(const f16x4*)(xb + (size_t)ng * FDIM + lane32 * 4);
    }
    const int swz = (nl & 7) << 4;
    *(f16x4*)(lds + nl * 512 + ((lane32 * 8) ^ swz))       = agg;  // k [0,128)
    *(f16x4*)(lds + nl * 512 + ((256 + lane32 * 8) ^ swz)) = xv;   // k [128,256)
  }

  __syncthreads();

  // ---- MFMA: D[64x128] = cc[64x256] . W^T, 16x16x32 f16, W hi/lo 2-term ----
  f32x4 acc[4][2] = {};
  #pragma unroll
  for (int h2 = 0; h2 < 2; ++h2) {
    #pragma unroll
    for (int kt = 0; kt < 4; ++kt) {
      const int k = h2 * 128 + kt * 32 + kg * 8;
      const f16x8 Bh0 = *(const f16x8*)(Wh + (o0 + col) * K2 + k);
      const f16x8 Bh1 = *(const f16x8*)(Wh + (o0 + 16 + col) * K2 + k);
      const f16x8 Bl0 = *(const f16x8*)(Wl + (o0 + col) * K2 + k);
      const f16x8 Bl1 = *(const f16x8*)(Wl + (o0 + 16 + col) * K2 + k);
      f16x8 Ah[4];
      #pragma unroll
      for (int mf = 0; mf < 4; ++mf) {
        const int row = mf * 16 + col;
        Ah[mf] = *(const f16x8*)(lds + row * 512 + ((k * 2) ^ ((row & 7) << 4)));
      }
      #pragma unroll
      for (int mf = 0; mf < 4; ++mf) {
        acc[mf][0] = __builtin_amdgcn_mfma_f32_16x16x32_f16(Ah[mf], Bh0, acc[mf][0], 0, 0, 0);
        acc[mf][0] = __builtin_amdgcn_mfma_f32_16x16x32_f16(Ah[mf], Bl0, acc[mf][0], 0, 0, 0);
        acc[mf][1] = __builtin_amdgcn_mfma_f32_16x16x32_f16(Ah[mf], Bh1, acc[mf][1], 0, 0, 0);
        acc[mf][1] = __builtin_amdgcn_mfma_f32_16x16x32_f16(Ah[mf], Bl1, acc[mf][1], 0, 0, 0);
      }
    }
  }

  // ---- epilogue: bias + relu + store (C/D: col=lane&15, row=(lane>>4)*4+j) ----
  const float bv0 = bias[o0 + col];
  const float bv1 = bias[o0 + 16 + col];
  #pragma unroll
  for (int mf = 0; mf < 4; ++mf) {
    #pragma unroll
    for (int j = 0; j < 4; ++j) {
      const int nl = mf * 16 + kg * 4 + j;
      const int ng = n0 + nl;
      if (ng < N_NODES) {
        const float r0 = fmaxf(acc[mf][0][j] + bv0, 0.f);
        const float r1 = fmaxf(acc[mf][1][j] + bv1, 0.f);
        if (OUT_F32) {
          float* orow = (float*)out_ + ((size_t)b * N_NODES + ng) * FDIM;
          orow[o0 + col]      = r0;
          orow[o0 + 16 + col] = r1;
        } else {
          _Float16* orow = (_Float16*)out_ + ((size_t)b * N_NODES + ng) * FDIM;
          orow[o0 + col]      = (_Float16)r0;
          orow[o0 + 16 + col] = (_Float16)r1;
        }
      }
    }
  }
}

extern "C" void kernel_launch(void* const* d_in, const int* in_sizes, int n_in,
                              void* d_out, int out_size, void* d_ws, size_t ws_size,
                              hipStream_t stream) {
  const float* x  = (const float*)d_in[0];
  const int* adj  = (const int*)d_in[1];
  const float* W1 = (const float*)d_in[2];
  const float* b1 = (const float*)d_in[3];
  const float* W2 = (const float*)d_in[4];
  const float* b2 = (const float*)d_in[5];
  float* out      = (float*)d_out;

  char* ws = (char*)d_ws;
  const size_t nElem = (size_t)N_BATCH * N_NODES * FDIM;  // 25.6M
  _Float16* x16   = (_Float16*)ws;                        // 51.2 MB
  _Float16* inter = x16 + nElem;                          // 51.2 MB
  _Float16* w1h   = inter + nElem;
  _Float16* w1l   = w1h + 32768;
  _Float16* w2h   = w1l + 32768;
  _Float16* w2l   = w2h + 32768;

  split_w_kernel<<<128, 256, 0, stream>>>(W1, W2, w1h, w1l, w2h, w2l);
  cvt_x_kernel<<<25000, 256, 0, stream>>>(x, x16);

  dim3 grid((N_NODES + TILE_M - 1) / TILE_M, N_BATCH);  // (782, 4)
  gnn_layer_kernel<false><<<grid, 256, 0, stream>>>(x16, adj, w1h, w1l, b1, inter);
  gnn_layer_kernel<true><<<grid, 256, 0, stream>>>(inter, adj, w2h, w2l, b2, out);
}

// Round 5
// 363.082 us; speedup vs baseline: 1.2907x; 1.1416x over previous
//
#include <hip/hip_runtime.h>

// IntersectionGNN: out = L2(L1(x)) with L(x) = relu([max_nbr(x) | x] @ W^T + b)
// B=4, N=50000, D=8, F=128, K=2F=256.
//
// Round 3 design (2nd resubmit — rounds 3/4 died infra-side before running):
//  - KEY: adj is batch-independent -> re-layout x/inter as (N,B,F) f16 so one
//    contiguous 1KB line holds all 4 batches of a node. Gather = one full-wave
//    coalesced 1KB load per neighbor (16B/lane), 4x fewer load instrs, adj read
//    once per node, zero cvt VALU in the layer kernel (max is in-lane).
//  - transpose_x pre-pass: (B,N,F) f32 -> (N,B,F) f16.
//  - GEMM: A = f16 cc, W f16 hi/lo -> acc = Ah*Bh + Ah*Bl (err ~5e-4 << 0.0156 resid).
//  - LDS 32KB (64 rows x 512B, XOR swizzle (row&7)<<4), __launch_bounds__(256,5)
//    -> 5 blocks/CU (round-2 counters: occ 37%, hbm 29%, latency-bound).
//  - layer-1 epilogue writes contiguous inter_T rows; layer-2 writes final f32
//    out with nontemporal stores (don't evict x16/inter from L3).
//  - d_ws: [xT 51.2MB][interT 51.2MB][W splits 256KB].

#define N_NODES 50000
#define N_BATCH 4
#define DEG 8
#define FDIM 128
#define K2 256
#define TILE_N 16  // nodes per block -> M = 64 rows (16 nodes x 4 batches)

typedef _Float16 f16x8 __attribute__((ext_vector_type(8)));
typedef _Float16 f16x4 __attribute__((ext_vector_type(4)));
typedef float f32x4 __attribute__((ext_vector_type(4)));

__global__ void split_w_kernel(const float* __restrict__ W1, const float* __restrict__ W2,
                               _Float16* __restrict__ w1h, _Float16* __restrict__ w1l,
                               _Float16* __restrict__ w2h, _Float16* __restrict__ w2l) {
  const int i = blockIdx.x * 256 + threadIdx.x;  // 128 blocks: exactly 128*256 = 32768
  {
    const float a = W1[i];
    const _Float16 h = (_Float16)a;
    w1h[i] = h;
    w1l[i] = (_Float16)(a - (float)h);
  }
  {
    const float a = W2[i];
    const _Float16 h = (_Float16)a;
    w2h[i] = h;
    w2l[i] = (_Float16)(a - (float)h);
  }
}

// (B,N,F) f32 -> (N,B,F) f16. One wave per node: lane = (b = l>>4, 8-col chunk).
__global__ void transpose_x_kernel(const float* __restrict__ x, _Float16* __restrict__ xT) {
  const int wv = threadIdx.x >> 6, l = threadIdx.x & 63;
  const int n = blockIdx.x * 4 + wv;  // grid 12500: exactly 50000 nodes
  const int b = l >> 4;
  const int c8 = (l & 15) * 8;
  const float* src = x + ((size_t)b * N_NODES + n) * FDIM + c8;
  const f32x4 v0 = *(const f32x4*)src;
  const f32x4 v1 = *(const f32x4*)(src + 4);
  f16x8 h;
  #pragma unroll
  for (int j = 0; j < 4; ++j) h[j] = (_Float16)v0[j];
  #pragma unroll
  for (int j = 0; j < 4; ++j) h[4 + j] = (_Float16)v1[j];
  *(f16x8*)(xT + ((size_t)n * N_BATCH + b) * FDIM + c8) = h;
}

static __device__ inline f16x8 vmax8(f16x8 a, f16x8 b) {
  f16x8 r;
  #pragma unroll
  for (int j = 0; j < 8; ++j) r[j] = a[j] > b[j] ? a[j] : b[j];
  return r;
}

template <bool OUT_F32>
__global__ __launch_bounds__(256, 5)
void gnn_layer_kernel(const _Float16* __restrict__ xT, const int* __restrict__ adj,
                      const _Float16* __restrict__ Wh, const _Float16* __restrict__ Wl,
                      const float* __restrict__ bias, void* __restrict__ out_) {
  __shared__ unsigned char lds[32768];  // cc f16: 64 rows x 512B, XOR-swizzled

  const int tid = (int)threadIdx.x;
  const int n0  = (int)blockIdx.x * TILE_N;  // grid 3125: exact

  const int l   = tid & 63;
  const int wv  = tid >> 6;   // wave 0..3
  const int col = l & 15;
  const int kg  = l >> 4;
  const int o0  = wv * 32;    // wave's output cols [o0, o0+32)

  // ---- gather-max (all-batch 1KB rows) + concat into LDS ----
  const int bb = l >> 4;         // batch
  const int c8 = (l & 15) * 8;   // f16 col base
  #pragma unroll 2
  for (int i = 0; i < 4; ++i) {
    const int nl = wv * 4 + i;   // wave handles nodes wv*4 .. wv*4+3
    const int ng = n0 + nl;
    const int* arow = adj + ng * DEG;
    const size_t laneoff = (size_t)bb * FDIM + c8;
    f16x8 v[DEG];
    #pragma unroll
    for (int d = 0; d < DEG; ++d)
      v[d] = *(const f16x8*)(xT + (size_t)arow[d] * (N_BATCH * FDIM) + laneoff);
    const f16x8 xv = *(const f16x8*)(xT + (size_t)ng * (N_BATCH * FDIM) + laneoff);
    const f16x8 agg = vmax8(vmax8(vmax8(v[0], v[1]), vmax8(v[2], v[3])),
                            vmax8(vmax8(v[4], v[5]), vmax8(v[6], v[7])));
    const int r   = nl * N_BATCH + bb;   // LDS/output row
    const int swz = (r & 7) << 4;
    *(f16x8*)(lds + r * 512 + ((c8 * 2) ^ swz))       = agg;  // k [0,128)
    *(f16x8*)(lds + r * 512 + (256 + ((c8 * 2) ^ swz))) = xv;  // k [128,256)
  }

  __syncthreads();

  // ---- MFMA: D[64x128] = cc[64x256] . W^T, 16x16x32 f16, W hi/lo 2-term ----
  f32x4 acc[4][2] = {};
  #pragma unroll
  for (int h2 = 0; h2 < 2; ++h2) {
    #pragma unroll
    for (int kt = 0; kt < 4; ++kt) {
      const int k = h2 * 128 + kt * 32 + kg * 8;
      const f16x8 Bh0 = *(const f16x8*)(Wh + (o0 + col) * K2 + k);
      const f16x8 Bh1 = *(const f16x8*)(Wh + (o0 + 16 + col) * K2 + k);
      const f16x8 Bl0 = *(const f16x8*)(Wl + (o0 + col) * K2 + k);
      const f16x8 Bl1 = *(const f16x8*)(Wl + (o0 + 16 + col) * K2 + k);
      f16x8 Ah[4];
      #pragma unroll
      for (int mf = 0; mf < 4; ++mf) {
        const int row = mf * 16 + col;
        const int kb  = k * 2;  // byte col; k>=128 lives at 256+((kb&255)^swz)
        Ah[mf] = *(const f16x8*)(lds + row * 512 +
                                 ((kb & 256) | ((kb & 255) ^ ((row & 7) << 4))));
      }
      #pragma unroll
      for (int mf = 0; mf < 4; ++mf) {
        acc[mf][0] = __builtin_amdgcn_mfma_f32_16x16x32_f16(Ah[mf], Bh0, acc[mf][0], 0, 0, 0);
        acc[mf][0] = __builtin_amdgcn_mfma_f32_16x16x32_f16(Ah[mf], Bl0, acc[mf][0], 0, 0, 0);
        acc[mf][1] = __builtin_amdgcn_mfma_f32_16x16x32_f16(Ah[mf], Bh1, acc[mf][1], 0, 0, 0);
        acc[mf][1] = __builtin_amdgcn_mfma_f32_16x16x32_f16(Ah[mf], Bl1, acc[mf][1], 0, 0, 0);
      }
    }
  }

  // ---- epilogue: bias + relu + store (C/D: col=lane&15, row=(lane>>4)*4+j) ----
  const float bv0 = bias[o0 + col];
  const float bv1 = bias[o0 + 16 + col];
  #pragma unroll
  for (int mf = 0; mf < 4; ++mf) {
    #pragma unroll
    for (int j = 0; j < 4; ++j) {
      const int r = mf * 16 + kg * 4 + j;  // block row = (node nl=r>>2, batch b=r&3)
      const float r0 = fmaxf(acc[mf][0][j] + bv0, 0.f);
      const float r1 = fmaxf(acc[mf][1][j] + bv1, 0.f);
      if (OUT_F32) {
        const int b = r & 3, n = n0 + (r >> 2);
        float* orow = (float*)out_ + ((size_t)b * N_NODES + n) * FDIM;
        __builtin_nontemporal_store(r0, &orow[o0 + col]);
        __builtin_nontemporal_store(r1, &orow[o0 + 16 + col]);
      } else {
        // inter_T row index = (n0 + (r>>2))*4 + (r&3) = n0*4 + r  (contiguous!)
        _Float16* orow = (_Float16*)out_ + ((size_t)n0 * N_BATCH + r) * FDIM;
        orow[o0 + col]      = (_Float16)r0;
        orow[o0 + 16 + col] = (_Float16)r1;
      }
    }
  }
}

extern "C" void kernel_launch(void* const* d_in, const int* in_sizes, int n_in,
                              void* d_out, int out_size, void* d_ws, size_t ws_size,
                              hipStream_t stream) {
  const float* x  = (const float*)d_in[0];
  const int* adj  = (const int*)d_in[1];
  const float* W1 = (const float*)d_in[2];
  const float* b1 = (const float*)d_in[3];
  const float* W2 = (const float*)d_in[4];
  const float* b2 = (const float*)d_in[5];
  float* out      = (float*)d_out;

  char* ws = (char*)d_ws;
  const size_t nElem = (size_t)N_BATCH * N_NODES * FDIM;  // 25.6M
  _Float16* xT    = (_Float16*)ws;  // (N,B,F) f16, 51.2 MB
  _Float16* inter = xT + nElem;     // (N,B,F) f16, 51.2 MB
  _Float16* w1h   = inter + nElem;
  _Float16* w1l   = w1h + 32768;
  _Float16* w2h   = w1l + 32768;
  _Float16* w2l   = w2h + 32768;

  split_w_kernel<<<128, 256, 0, stream>>>(W1, W2, w1h, w1l, w2h, w2l);
  transpose_x_kernel<<<12500, 256, 0, stream>>>(x, xT);

  const int grid = N_NODES / TILE_N;  // 3125
  gnn_layer_kernel<false><<<grid, 256, 0, stream>>>(xT, adj, w1h, w1l, b1, inter);
  gnn_layer_kernel<true><<<grid, 256, 0, stream>>>(inter, adj, w2h, w2l, b2, out);
}